// Round 4
// baseline (408.534 us; speedup 1.0000x reference)
//
#include <hip/hip_runtime.h>
#include <cmath>

// ---------------------------------------------------------------------------
// Fused 3D SSIM, separable Gaussian 11-tap, VALID. fp32 (2,1,192,192,192).
// z-streaming slab, 512 threads, ONE output column per thread, channel-packed
// v_pk_fma_f32 math (r2 structure, 225 us, occupancy 37%).
//
// Round-4: raw-input LDS prefetch (one plane ahead) via global_load_lds into
// PER-WAVE slabs — r3's design, with the DMA width moved from size=12 to the
// HW-VERIFIED size=16 path.
//   r3 FAILED correctness (absmax 0.16): it assumed dwordx3 LDS-DMA strides
//   lanes at 12 B (base + 12*lane). Only size=4 and size=16 have verified
//   lane-stride semantics (dest = wave-uniform base + lane*size); dwordx3's
//   LDS stride is undocumented. r4 uses size=16: lane l fills 16 B at
//   base + 16*lane -> one wave = 1024 B = 4 rows x 64 cols fp32 exactly.
//   Evidence driving the design: r0 (3 waves/SIMD) and r2 (4 waves/SIMD)
//   both sit at VALUBusy ~46% -> occupancy is not the lever; the per-plane
//   global-load->use stall inside the barrier-to-barrier path is.
//   Slab of wave w is written AND read only by wave w -> no barrier needed,
//   wave-local s_waitcnt vmcnt(0) at W-top only. Issue is AFTER
//   __syncthreads so the barrier's implicit vmcnt(0) drain is always
//   already satisfied; load latency hides under H+D+SSIM of the previous
//   plane. Zero extra per-thread registers (r1's register prefetch paid
//   +24 VGPR = a wave tier, -19%).
//
// REVERT CUE: WRITE_SIZE ballooning (MBs->GBs) = spill (r6 signature).
// DO NOT: size=12 global_load_lds (r3: corrupts, unverified lane stride);
//         register-prefetch (r1: -19%); 2-deep LDS prefetch (next barrier's
//         vmcnt(0) drain would serialize it).
// ---------------------------------------------------------------------------

#define WSZ 11
#define DIN 192
#define DOUTS 182
#define TH 16              // tile height (output rows, y)
#define TWD 32             // tile width  (output cols, x)
#define IHR 26             // input rows per plane tile (TH + 10)
#define ZCH 24             // output planes per chunk
#define ZIN 34             // input planes per chunk (ZCH + 10)
#define NTX 6              // x tiles (6*32 = 192)
#define NTY 12             // y tiles (12*16 = 192)
#define ZC 8               // z-chunks (8*24 = 192)
#define NBLK (NTX*NTY*2*ZC)  // 1152
#define LSTR (TWD+2)       // LDS row stride 34: even (8B-align) + conflict-free
#define RROWS 4            // raw slab rows per wave
#define RCOLS 64           // raw slab cols: 64 lanes x 16 B = 4 x 64 floats
#define NWV 7              // waves owning W rows (ceil(26/4))
static constexpr double SOUT = 2.0 * 182.0 * 182.0 * 182.0;  // 12,057,136

typedef float v2f __attribute__((ext_vector_type(2)));

struct G11 { float g[WSZ]; };

__device__ __forceinline__ v2f pkfma(float g, v2f v, v2f a) {
    v2f gg = {g, g};
    return __builtin_elementwise_fma(gg, v, a);
}

__device__ __forceinline__ unsigned int enc_f(float f) {
    unsigned int u = __float_as_uint(f);
    return (u & 0x80000000u) ? ~u : (u | 0x80000000u);
}
__device__ __forceinline__ float dec_f(unsigned int u) {
    return (u & 0x80000000u) ? __uint_as_float(u & 0x7FFFFFFFu) : __uint_as_float(~u);
}

// global -> LDS async copy, 16 B/lane (dwordx4): 64 lanes fill 1024 B
// contiguously (lane l -> LDS base + 16*l). HW-verified lane stride.
#define GLOAD_LDS16(G, L)                                                     \
    __builtin_amdgcn_global_load_lds(                                         \
        (const __attribute__((address_space(1))) void*)(G),                   \
        (__attribute__((address_space(3))) void*)(L), 16, 0, 0)

// ---------------------------------------------------------------------------
__global__ void k_init(unsigned int* mm, double* sum) {
    sum[0] = 0.0;
    mm[0] = 0u;           // encoded -inf (max accumulator)
    mm[1] = 0xFFFFFFFFu;  // encoded +inf (min accumulator)
}

// ---------------------------------------------------------------------------
__global__ __launch_bounds__(256) void k_minmax(const float4* __restrict__ img1,
                                                int n4, unsigned int* mm) {
    float mx = -1e30f, mn = 1e30f;
    for (int i = blockIdx.x * blockDim.x + threadIdx.x; i < n4;
         i += gridDim.x * blockDim.x) {
        float4 v = img1[i];
        mx = fmaxf(mx, fmaxf(fmaxf(v.x, v.y), fmaxf(v.z, v.w)));
        mn = fminf(mn, fminf(fminf(v.x, v.y), fminf(v.z, v.w)));
    }
    #pragma unroll
    for (int o = 32; o; o >>= 1) {
        mx = fmaxf(mx, __shfl_down(mx, o));
        mn = fminf(mn, __shfl_down(mn, o));
    }
    __shared__ float smx[4], smn[4];
    int lane = threadIdx.x & 63, wv = threadIdx.x >> 6;
    if (lane == 0) { smx[wv] = mx; smn[wv] = mn; }
    __syncthreads();
    if (threadIdx.x == 0) {
        #pragma unroll
        for (int i = 1; i < 4; i++) { mx = fmaxf(mx, smx[i]); mn = fminf(mn, smn[i]); }
        atomicMax(&mm[0], enc_f(mx));
        atomicMin(&mm[1], enc_f(mn));
    }
}

// ---------------------------------------------------------------------------
// 512 threads, tile 32(x) x 16(y), thread owns ONE output column.
// launch_bounds(512,4): reg cap 128 -> 4 waves/SIMD (2 blocks/CU).
__global__ __launch_bounds__(512, 4) void k_ssim(const float* __restrict__ img1,
                                                 const float* __restrict__ img2,
                                                 const unsigned int* __restrict__ mm,
                                                 double* __restrict__ sum, G11 gw) {
    // Channel-interleaved, double-buffered W-conv planes (35.4 KB):
    //   twsA[h][x] = (mu1, mu2)   twsB[h][x] = (E11, E22)   twsC[h][x] = E12
    __shared__ float twsA[2][IHR][LSTR][2];
    __shared__ float twsB[2][IHR][LSTR][2];
    __shared__ float twsC[2][IHR][LSTR];
    // Per-wave raw-input slabs, double-buffered (28.7 KB). Slab of wave w is
    // written AND read only by wave w -> no barrier needed, vmcnt-only.
    __shared__ float rawS[2][NWV][2][RROWS][RCOLS];
    __shared__ float sred[8];

    int b   = blockIdx.x;
    int twi = b % NTX;
    int thi = (b / NTX) % NTY;
    int rest = b / (NTX * NTY);
    int tc  = rest % ZC;
    int n   = rest / ZC;                 // batch 0..1
    int ow0 = twi * TWD, oh0 = thi * TH, od0 = tc * ZCH;
    int tid = threadIdx.x;
    int y = tid >> 5, x = tid & 31;      // thread owns output (y, x)
    int wv = tid >> 6, lane = tid & 63;  // wave id / lane id

    // SSIM constants (L from img1 min/max, computed by k_minmax)
    float maxv = dec_f(mm[0]);
    float minv = dec_f(mm[1]);
    float max_val = (maxv > 128.0f) ? 255.0f : 1.0f;
    float min_val = (minv < -0.5f) ? -1.0f : 0.0f;
    float L  = max_val - min_val;
    float C1 = 0.01f * L; C1 *= C1;
    float C2 = 0.03f * L; C2 *= C2;

    bool vout = (oh0 + y < DOUTS) && (ow0 + x < DOUTS);

    // W-item geometry: 416 pair-items (row wh in [0,26), x-pair wxp in [0,16)),
    // one per thread for tid < 416. Wave w's items are rows [4w, 4w+4) ==
    // exactly its raw slab. Clamped rows/cols feed only masked outputs.
    int wh  = tid >> 4, wxp = tid & 15;
    bool wact = (tid < IHR * 16);

    // Raw slab geometry (loop-invariant).
    int xbase = min(ow0, DIN - RCOLS);            // 0..128 (right-edge shift)
    int ybase = min(oh0 + 4 * wv, DIN - RROWS);   // wave slab row base
    // 16B/lane fill: lane l -> slab floats [4l, 4l+4) = (row l>>4, col 4*(l&15))
    int srow = ybase + (lane >> 4);
    int scol = xbase + 4 * (lane & 15);           // <= 128+60=188, +4 floats OK
    const size_t nbase = (size_t)n * DIN * DIN * DIN;
    const float* gsrc1 = img1 + nbase + (size_t)srow * DIN + scol;
    const float* gsrc2 = img2 + nbase + (size_t)srow * DIN + scol;
    // W item coords inside the slab (loop-invariant):
    int lr = min(oh0 + wh, DIN - 1) - ybase;        // 0..3 for wact threads
    int lc = min(ow0 + 2 * wxp, DIN - 12) - xbase;  // even, 0..52; +11 <= 63

    // D-conv packed shift pipeline: index j covers output zo = zi - j.
    v2f accMu[WSZ], accE[WSZ];
    float acc12[WSZ];
    float local = 0.f;

    // ---- prologue: issue raw slab for plane 0 into buf 0 ----
    if (wv < NWV) {
        size_t z0 = (size_t)min(od0, DIN - 1) * (size_t)(DIN * DIN);
        GLOAD_LDS16(gsrc1 + z0, &rawS[0][wv][0][0][0]);
        GLOAD_LDS16(gsrc2 + z0, &rawS[0][wv][1][0][0]);
    }

    for (int zi = 0; zi < ZIN; zi++) {
        int buf = zi & 1;

        // wave-local: this plane's slab loads (issued one plane ago) complete.
        asm volatile("s_waitcnt vmcnt(0)" ::: "memory");

        // ---- W phase: x-conv from the LDS slab, (img1,img2) packed ----
        if (wact) {
            const v2f* q1 = (const v2f*)&rawS[buf][wv][0][lr][lc];
            const v2f* q2 = (const v2f*)&rawS[buf][wv][1][lr][lc];
            v2f p[12];                               // lane-pair = (img1, img2)
            #pragma unroll
            for (int q = 0; q < 6; q++) {
                v2f f1 = q1[q];
                v2f f2 = q2[q];
                p[2*q]   = (v2f){f1.x, f2.x};
                p[2*q+1] = (v2f){f1.y, f2.y};
            }
            v2f amu[2] = {{0.f,0.f},{0.f,0.f}};      // (mu1, mu2) per output
            v2f asq[2] = {{0.f,0.f},{0.f,0.f}};      // (E11, E22) per output
            float a12[2] = {0.f, 0.f};               // E12 per output
            #pragma unroll
            for (int k = 0; k < WSZ; k++) {
                float g = gw.g[k];
                #pragma unroll
                for (int o = 0; o < 2; o++) {
                    v2f e = p[k + o];
                    v2f t = (v2f){g, g} * e;         // pk_mul
                    amu[o] += t;                     // pk_add
                    asq[o] = __builtin_elementwise_fma(t, e, asq[o]);  // pk_fma
                    a12[o] = fmaf(t.x, e.y, a12[o]); // cross term
                }
            }
            int xo = 2 * wxp;
            *(v2f*)&twsA[buf][wh][xo][0]     = amu[0];   // merges to b128
            *(v2f*)&twsA[buf][wh][xo + 1][0] = amu[1];
            *(v2f*)&twsB[buf][wh][xo][0]     = asq[0];
            *(v2f*)&twsB[buf][wh][xo + 1][0] = asq[1];
            *(v2f*)&twsC[buf][wh][xo]        = (v2f){a12[0], a12[1]};
        }
        __syncthreads();   // only barrier/plane; vmcnt already 0 here (no drain)

        // ---- issue NEXT plane's raw slab; hides under H + D + SSIM ----
        if (zi + 1 < ZIN && wv < NWV) {
            size_t zn = (size_t)min(od0 + zi + 1, DIN - 1) * (size_t)(DIN * DIN);
            GLOAD_LDS16(gsrc1 + zn, &rawS[buf ^ 1][wv][0][0][0]);
            GLOAD_LDS16(gsrc2 + zn, &rawS[buf ^ 1][wv][1][0][0]);
        }

        // ---- H phase: y-conv, channel-packed ds_read_b64 per (k) ----
        v2f mMu = {0.f, 0.f}, mE = {0.f, 0.f};
        float m12 = 0.f;
        #pragma unroll
        for (int k = 0; k < WSZ; k++) {
            float g = gw.g[k];
            mMu = pkfma(g, *(const v2f*)&twsA[buf][y + k][x][0], mMu);
            mE  = pkfma(g, *(const v2f*)&twsB[buf][y + k][x][0], mE);
            m12 = fmaf(g, twsC[buf][y + k][x], m12);
        }
        // No second barrier: W(zi+2) reuses this tws buffer only after every
        // wave passes barrier(zi+1). Raw slabs are wave-private (vmcnt-only).

        // ---- D shift-FMA (channel-packed): acc[j] = g[j]*m + acc[j-1] ----
        #pragma unroll
        for (int j = WSZ - 1; j >= 1; j--) {
            accMu[j] = pkfma(gw.g[j], mMu, accMu[j-1]);
            accE[j]  = pkfma(gw.g[j], mE,  accE[j-1]);
            acc12[j] = fmaf(gw.g[j], m12, acc12[j-1]);
        }
        accMu[0] = (v2f){gw.g[0], gw.g[0]} * mMu;
        accE[0]  = (v2f){gw.g[0], gw.g[0]} * mE;
        acc12[0] = gw.g[0] * m12;

        // ---- SSIM for completed output plane zo = zi - 10 ----
        if (zi >= WSZ - 1) {
            int zo = od0 + zi - (WSZ - 1);
            if (zo < DOUTS && vout) {
                float mu1 = accMu[10].x, mu2 = accMu[10].y;
                float mu1s = mu1 * mu1, mu2s = mu2 * mu2, mu12 = mu1 * mu2;
                float s1  = accE[10].x - mu1s;
                float s2  = accE[10].y - mu2s;
                float s12 = acc12[10] - mu12;
                float v1  = 2.f * s12 + C2;
                float v2  = s1 + s2 + C2;
                float num = (2.f * mu12 + C1) * v1;
                float den = (mu1s + mu2s + C1) * v2;
                local += num / den;
            }
        }
    }

    // ---- block reduction (8 waves) -> one f64 atomic ----
    #pragma unroll
    for (int o = 32; o; o >>= 1) local += __shfl_down(local, o);
    if ((tid & 63) == 0) sred[tid >> 6] = local;
    __syncthreads();
    if (tid == 0) {
        float t = 0.f;
        #pragma unroll
        for (int i = 0; i < 8; i++) t += sred[i];
        atomicAdd(sum, (double)t);
    }
}

// ---------------------------------------------------------------------------
__global__ void k_final(const double* __restrict__ sum, float* __restrict__ out) {
    out[0] = (float)(sum[0] / SOUT);
}

// ---------------------------------------------------------------------------
extern "C" void kernel_launch(void* const* d_in, const int* in_sizes, int n_in,
                              void* d_out, int out_size, void* d_ws, size_t ws_size,
                              hipStream_t stream) {
    const float* img1 = (const float*)d_in[0];
    const float* img2 = (const float*)d_in[1];
    float* out = (float*)d_out;

    char* ws = (char*)d_ws;
    double*       sum = (double*)ws;              // 8 B
    unsigned int* mm  = (unsigned int*)(ws + 8);  // 8 B

    // Gaussian weights: f64 compute, normalize, cast to f32 (matches ref).
    G11 g;
    {
        double gd[WSZ], s = 0.0;
        for (int i = 0; i < WSZ; i++) {
            double d = (double)(i - WSZ / 2);
            gd[i] = std::exp(-(d * d) / (2.0 * 1.5 * 1.5));
            s += gd[i];
        }
        for (int i = 0; i < WSZ; i++) g.g[i] = (float)(gd[i] / s);
    }

    int n_img = 2 * DIN * DIN * DIN;  // 14,155,776

    k_init<<<1, 1, 0, stream>>>(mm, sum);
    k_minmax<<<2048, 256, 0, stream>>>((const float4*)img1, n_img / 4, mm);
    k_ssim<<<NBLK, 512, 0, stream>>>(img1, img2, mm, sum, g);
    k_final<<<1, 1, 0, stream>>>(sum, out);
}

// Round 5
// 342.418 us; speedup vs baseline: 1.1931x; 1.1931x over previous
//
#include <hip/hip_runtime.h>
#include <cmath>

// ---------------------------------------------------------------------------
// Fused 3D SSIM, separable Gaussian 11-tap, VALID. fp32 (2,1,192,192,192).
// z-streaming slab, 512 threads, ONE output column per thread, channel-packed
// v_pk_fma_f32 math (r2 structure: 225 us steady, occupancy 37%).
//
// Round-5 change (isolated): TWO PLANES PER PHASE (17 phases of 2, was 34
// phases of 1). Same single-barrier-per-phase double-buffer scheme.
//   Evidence: r0 (3 w/SIMD) and r2 (4 w/SIMD) both sit at VALUBusy ~46%;
//   r1/r4 proved neither register- nor LDS-prefetch of W inputs helps ->
//   load latency is already hidden; occupancy is not the lever. Remaining
//   consumers of the ~50% non-VALU cycles all scale with PHASE COUNT:
//   34 barrier convergences (W-phase wave imbalance: wave 7 idle), 34
//   latency-exposed H chains (3 serial 11-FMA reductions), 34x loop fixed
//   cost. 2 planes/phase: halves barriers, 2x ILP across the two planes'
//   independent H chains, W items 832/512 (waves 0-4: 2 items, 5-7: 1 --
//   smaller idle bubble), fixed costs amortize 2x.
//   Cost: tws LDS 35.4 -> 70.7 KB (2 blocks/CU: 141.5 <= 160 KB, residency
//   unchanged), +10 VGPR for plane-1 m values (W items kept SEQUENTIAL to
//   cap live range).
//
// REVERT CUE: WRITE_SIZE ballooning (MBs->GBs) = spill (r6 signature).
// DO NOT: register-prefetch W inputs (r1: -19%, costs a wave tier);
//         global_load_lds slab prefetch (r4: -20%, vmcnt(0) ordering +
//         DS-pipe contention); size=12 LDS-DMA (r3: corrupts).
// ---------------------------------------------------------------------------

#define WSZ 11
#define DIN 192
#define DOUTS 182
#define TH 16              // tile height (output rows, y)
#define TWD 32             // tile width  (output cols, x)
#define IHR 26             // input rows per plane tile (TH + 10)
#define ZCH 24             // output planes per chunk
#define ZIN 34             // input planes per chunk (ZCH + 10)
#define NPH (ZIN/2)        // 17 two-plane phases
#define NTX 6              // x tiles (6*32 = 192)
#define NTY 12             // y tiles (12*16 = 192)
#define ZC 8               // z-chunks (8*24 = 192)
#define NBLK (NTX*NTY*2*ZC)  // 1152
#define LSTR (TWD+2)       // LDS row stride 34: even (8B-align) + conflict-free
#define WITEMS (IHR*16)    // 416 W pair-items per plane
static constexpr double SOUT = 2.0 * 182.0 * 182.0 * 182.0;  // 12,057,136

typedef float v2f __attribute__((ext_vector_type(2)));

struct G11 { float g[WSZ]; };

__device__ __forceinline__ v2f pkfma(float g, v2f v, v2f a) {
    v2f gg = {g, g};
    return __builtin_elementwise_fma(gg, v, a);
}

__device__ __forceinline__ unsigned int enc_f(float f) {
    unsigned int u = __float_as_uint(f);
    return (u & 0x80000000u) ? ~u : (u | 0x80000000u);
}
__device__ __forceinline__ float dec_f(unsigned int u) {
    return (u & 0x80000000u) ? __uint_as_float(u & 0x7FFFFFFFu) : __uint_as_float(~u);
}

// ---------------------------------------------------------------------------
__global__ void k_init(unsigned int* mm, double* sum) {
    sum[0] = 0.0;
    mm[0] = 0u;           // encoded -inf (max accumulator)
    mm[1] = 0xFFFFFFFFu;  // encoded +inf (min accumulator)
}

// ---------------------------------------------------------------------------
__global__ __launch_bounds__(256) void k_minmax(const float4* __restrict__ img1,
                                                int n4, unsigned int* mm) {
    float mx = -1e30f, mn = 1e30f;
    for (int i = blockIdx.x * blockDim.x + threadIdx.x; i < n4;
         i += gridDim.x * blockDim.x) {
        float4 v = img1[i];
        mx = fmaxf(mx, fmaxf(fmaxf(v.x, v.y), fmaxf(v.z, v.w)));
        mn = fminf(mn, fminf(fminf(v.x, v.y), fminf(v.z, v.w)));
    }
    #pragma unroll
    for (int o = 32; o; o >>= 1) {
        mx = fmaxf(mx, __shfl_down(mx, o));
        mn = fminf(mn, __shfl_down(mn, o));
    }
    __shared__ float smx[4], smn[4];
    int lane = threadIdx.x & 63, wv = threadIdx.x >> 6;
    if (lane == 0) { smx[wv] = mx; smn[wv] = mn; }
    __syncthreads();
    if (threadIdx.x == 0) {
        #pragma unroll
        for (int i = 1; i < 4; i++) { mx = fmaxf(mx, smx[i]); mn = fminf(mn, smn[i]); }
        atomicMax(&mm[0], enc_f(mx));
        atomicMin(&mm[1], enc_f(mn));
    }
}

// ---------------------------------------------------------------------------
// 512 threads, tile 32(x) x 16(y), thread owns ONE output column.
// launch_bounds(512,4): reg cap 128 -> 4 waves/SIMD (2 blocks/CU).
__global__ __launch_bounds__(512, 4) void k_ssim(const float* __restrict__ img1,
                                                 const float* __restrict__ img2,
                                                 const unsigned int* __restrict__ mm,
                                                 double* __restrict__ sum, G11 gw) {
    // Channel-interleaved W-conv planes: [dbuf][plane-in-phase][...], 70.7 KB.
    //   twsA[h][x] = (mu1, mu2)   twsB[h][x] = (E11, E22)   twsC[h][x] = E12
    __shared__ float twsA[2][2][IHR][LSTR][2];
    __shared__ float twsB[2][2][IHR][LSTR][2];
    __shared__ float twsC[2][2][IHR][LSTR];
    __shared__ float sred[8];

    int b   = blockIdx.x;
    int twi = b % NTX;
    int thi = (b / NTX) % NTY;
    int rest = b / (NTX * NTY);
    int tc  = rest % ZC;
    int n   = rest / ZC;                 // batch 0..1
    int ow0 = twi * TWD, oh0 = thi * TH, od0 = tc * ZCH;
    int tid = threadIdx.x;
    int y = tid >> 5, x = tid & 31;      // thread owns output (y, x)

    // SSIM constants (L from img1 min/max, computed by k_minmax)
    float maxv = dec_f(mm[0]);
    float minv = dec_f(mm[1]);
    float max_val = (maxv > 128.0f) ? 255.0f : 1.0f;
    float min_val = (minv < -0.5f) ? -1.0f : 0.0f;
    float L  = max_val - min_val;
    float C1 = 0.01f * L; C1 *= C1;
    float C2 = 0.03f * L; C2 *= C2;

    bool vout = (oh0 + y < DOUTS) && (ow0 + x < DOUTS);

    const size_t nbase = (size_t)n * DIN * DIN * DIN;

    // D-conv packed shift pipeline: index j covers output zo = zi - j.
    v2f accMu[WSZ], accE[WSZ];
    float acc12[WSZ];
    float local = 0.f;

    for (int t = 0; t < NPH; t++) {
        int buf = t & 1;

        // ---- W phase: 832 pair-items (2 planes x 416) over 512 threads ----
        // item u: plane pl = u/416, idx = u%416 -> row wh = idx/16, xpair idx%16.
        // Clamped rows/cols/planes feed only masked outputs.
        for (int u = tid; u < 2 * WITEMS; u += 512) {
            int pl  = (u >= WITEMS);
            int idx = u - pl * WITEMS;
            int wh  = idx >> 4, wxp = idx & 15;
            int d  = min(od0 + 2 * t + pl, DIN - 1);
            int hr = min(oh0 + wh, DIN - 1);
            int s  = min(ow0 + 2 * wxp, DIN - 12);   // even -> 8B-aligned
            const float2* p1 = (const float2*)(img1 + nbase + ((size_t)d * DIN + hr) * DIN + s);
            const float2* p2 = (const float2*)(img2 + nbase + ((size_t)d * DIN + hr) * DIN + s);
            v2f p[12];                               // lane-pair = (img1, img2)
            #pragma unroll
            for (int q = 0; q < 6; q++) {
                float2 f1 = p1[q];
                float2 f2 = p2[q];
                p[2*q]   = (v2f){f1.x, f2.x};
                p[2*q+1] = (v2f){f1.y, f2.y};
            }
            v2f amu[2] = {{0.f,0.f},{0.f,0.f}};      // (mu1, mu2) per output
            v2f asq[2] = {{0.f,0.f},{0.f,0.f}};      // (E11, E22) per output
            float a12[2] = {0.f, 0.f};               // E12 per output
            #pragma unroll
            for (int k = 0; k < WSZ; k++) {
                float g = gw.g[k];
                #pragma unroll
                for (int o = 0; o < 2; o++) {
                    v2f e = p[k + o];
                    v2f tt = (v2f){g, g} * e;        // pk_mul
                    amu[o] += tt;                    // pk_add
                    asq[o] = __builtin_elementwise_fma(tt, e, asq[o]);  // pk_fma
                    a12[o] = fmaf(tt.x, e.y, a12[o]); // cross term
                }
            }
            int xo = 2 * wxp;
            *(v2f*)&twsA[buf][pl][wh][xo][0]     = amu[0];   // merges to b128
            *(v2f*)&twsA[buf][pl][wh][xo + 1][0] = amu[1];
            *(v2f*)&twsB[buf][pl][wh][xo][0]     = asq[0];
            *(v2f*)&twsB[buf][pl][wh][xo + 1][0] = asq[1];
            *(v2f*)&twsC[buf][pl][wh][xo]        = (v2f){a12[0], a12[1]};
        }
        __syncthreads();   // only barrier per phase (2 planes)

        // ---- H phase: y-conv for BOTH planes (independent chains, 2x ILP) --
        v2f mMu[2], mE[2];
        float m12[2];
        #pragma unroll
        for (int pl = 0; pl < 2; pl++) {
            v2f aMu = {0.f, 0.f}, aE = {0.f, 0.f};
            float a12 = 0.f;
            #pragma unroll
            for (int k = 0; k < WSZ; k++) {
                float g = gw.g[k];
                aMu = pkfma(g, *(const v2f*)&twsA[buf][pl][y + k][x][0], aMu);
                aE  = pkfma(g, *(const v2f*)&twsB[buf][pl][y + k][x][0], aE);
                a12 = fmaf(g, twsC[buf][pl][y + k][x], a12);
            }
            mMu[pl] = aMu; mE[pl] = aE; m12[pl] = a12;
        }
        // No second barrier: W(t+2) reuses this dbuf half only after every
        // wave passes barrier(t+1), which follows every wave's H(t). [r2-proven]

        // ---- D shift-FMA + SSIM, once per plane ----
        #pragma unroll
        for (int pl = 0; pl < 2; pl++) {
            #pragma unroll
            for (int j = WSZ - 1; j >= 1; j--) {
                accMu[j] = pkfma(gw.g[j], mMu[pl], accMu[j-1]);
                accE[j]  = pkfma(gw.g[j], mE[pl],  accE[j-1]);
                acc12[j] = fmaf(gw.g[j], m12[pl], acc12[j-1]);
            }
            accMu[0] = (v2f){gw.g[0], gw.g[0]} * mMu[pl];
            accE[0]  = (v2f){gw.g[0], gw.g[0]} * mE[pl];
            acc12[0] = gw.g[0] * m12[pl];

            int zi = 2 * t + pl;
            if (zi >= WSZ - 1) {
                int zo = od0 + zi - (WSZ - 1);
                if (zo < DOUTS && vout) {
                    float mu1 = accMu[10].x, mu2 = accMu[10].y;
                    float mu1s = mu1 * mu1, mu2s = mu2 * mu2, mu12 = mu1 * mu2;
                    float s1  = accE[10].x - mu1s;
                    float s2  = accE[10].y - mu2s;
                    float s12 = acc12[10] - mu12;
                    float v1  = 2.f * s12 + C2;
                    float v2  = s1 + s2 + C2;
                    float num = (2.f * mu12 + C1) * v1;
                    float den = (mu1s + mu2s + C1) * v2;
                    local += num / den;
                }
            }
        }
    }

    // ---- block reduction (8 waves) -> one f64 atomic ----
    #pragma unroll
    for (int o = 32; o; o >>= 1) local += __shfl_down(local, o);
    if ((tid & 63) == 0) sred[tid >> 6] = local;
    __syncthreads();
    if (tid == 0) {
        float tsum = 0.f;
        #pragma unroll
        for (int i = 0; i < 8; i++) tsum += sred[i];
        atomicAdd(sum, (double)tsum);
    }
}

// ---------------------------------------------------------------------------
__global__ void k_final(const double* __restrict__ sum, float* __restrict__ out) {
    out[0] = (float)(sum[0] / SOUT);
}

// ---------------------------------------------------------------------------
extern "C" void kernel_launch(void* const* d_in, const int* in_sizes, int n_in,
                              void* d_out, int out_size, void* d_ws, size_t ws_size,
                              hipStream_t stream) {
    const float* img1 = (const float*)d_in[0];
    const float* img2 = (const float*)d_in[1];
    float* out = (float*)d_out;

    char* ws = (char*)d_ws;
    double*       sum = (double*)ws;              // 8 B
    unsigned int* mm  = (unsigned int*)(ws + 8);  // 8 B

    // Gaussian weights: f64 compute, normalize, cast to f32 (matches ref).
    G11 g;
    {
        double gd[WSZ], s = 0.0;
        for (int i = 0; i < WSZ; i++) {
            double d = (double)(i - WSZ / 2);
            gd[i] = std::exp(-(d * d) / (2.0 * 1.5 * 1.5));
            s += gd[i];
        }
        for (int i = 0; i < WSZ; i++) g.g[i] = (float)(gd[i] / s);
    }

    int n_img = 2 * DIN * DIN * DIN;  // 14,155,776

    k_init<<<1, 1, 0, stream>>>(mm, sum);
    k_minmax<<<2048, 256, 0, stream>>>((const float4*)img1, n_img / 4, mm);
    k_ssim<<<NBLK, 512, 0, stream>>>(img1, img2, mm, sum, g);
    k_final<<<1, 1, 0, stream>>>(sum, out);
}